// Round 1
// baseline (2833.805 us; speedup 1.0000x reference)
//
#include <hip/hip_runtime.h>
#include <math.h>

// AdaptiveScatteringNetwork: 2D scattering transform (J=6, L=4, S=128, B=64) + MLP.
// Strategy: whole 128x128 complex plane resident in LDS (split re/im, pitch 129
// to kill column-pass bank conflicts). Radix-2 DIF forward (natural->bitrev),
// radix-2 DIT inverse (bitrev->natural). Filters pre-permuted to bit-reversed
// 2D order with the 1/N ifft scale folded in, so no bit-reversal pass exists.

#define SDIM 128
#define PLANE 16384          // 128*128
#define PITCH 129            // +1 padding: column stride 129 words -> bank cycle 1
#define NT 1024              // threads per FFT workgroup (16 waves)
#define EPT 16               // PLANE / NT elements per thread
#define TWO_PI 6.28318530717958647692f

__device__ __forceinline__ int brev7(int x) { return (int)(__brev((unsigned)x) >> 25); }

// One 7-stage radix-2 pass along rows (rows=true) or columns (rows=false).
// forward: DIF, half = 64..1 ; inverse: DIT, half = 1..64 (twiddle conjugated).
// Butterfly index is wave-uniform (twiddle load is an LDS broadcast); the
// orthogonal coordinate is tid&127 so 64 lanes hit 32 banks 2-way (free).
__device__ __forceinline__ void fft_stages(float* __restrict__ sRe, float* __restrict__ sIm,
                                           const float* __restrict__ twR,
                                           const float* __restrict__ twI,
                                           int tid, bool rows, bool inverse) {
  const int orth = tid & 127;
  const int t7 = tid >> 7;
  for (int s = 0; s < 7; ++s) {
    const int lh = inverse ? s : 6 - s;   // log2(half)
    const int half = 1 << lh;
    const int tsh = 6 - lh;               // twiddle idx = j << tsh
    __syncthreads();
#pragma unroll
    for (int k = 0; k < 8; ++k) {
      const int bidx = (k << 3) | t7;                 // 0..63, wave-uniform
      const int j = bidx & (half - 1);
      const int i1 = ((bidx >> lh) << (lh + 1)) | j;
      const int i2 = i1 + half;
      const int a1 = rows ? (orth * PITCH + i1) : (i1 * PITCH + orth);
      const int a2 = rows ? (orth * PITCH + i2) : (i2 * PITCH + orth);
      const float wr = twR[j << tsh];
      const float wi = twI[j << tsh];
      const float ur = sRe[a1], ui = sIm[a1];
      const float vr = sRe[a2], vi = sIm[a2];
      if (inverse) {
        // w_inv = conj(w) = (wr, -wi); t = v * w_inv
        const float tr = vr * wr + vi * wi;
        const float ti = vi * wr - vr * wi;
        sRe[a1] = ur + tr; sIm[a1] = ui + ti;
        sRe[a2] = ur - tr; sIm[a2] = ui - ti;
      } else {
        const float dr = ur - vr, di = ui - vi;
        sRe[a1] = ur + vr; sIm[a1] = ui + vi;
        sRe[a2] = dr * wr - di * wi;
        sIm[a2] = dr * wi + di * wr;
      }
    }
  }
}

__device__ __forceinline__ void init_twiddles(float* twR, float* twI, int tid) {
  if (tid < 64) {
    const float ang = -TWO_PI * (float)tid * (1.0f / 128.0f);
    twR[tid] = cosf(ang);
    twI[tid] = sinf(ang);
  }
}

// returns full block sum on tid 0 only
__device__ __forceinline__ float block_reduce_sum(float v, float* red, int tid) {
#pragma unroll
  for (int o = 32; o > 0; o >>= 1) v += __shfl_down(v, o);
  __syncthreads();                 // protect red[] from prior use
  if ((tid & 63) == 0) red[tid >> 6] = v;
  __syncthreads();
  float t = 0.0f;
  if (tid == 0) {
#pragma unroll
    for (int w = 0; w < 16; ++w) t += red[w];
  }
  return t;
}

// K0: psi_br[p][r][c] = mags[p][br(r)][br(c)] * exp(i*phase) * (1/16384)
__global__ __launch_bounds__(256) void k_psi(const float* __restrict__ mags,
                                             const float* __restrict__ phases,
                                             float2* __restrict__ psi) {
  const int gid = blockIdx.x * 256 + threadIdx.x;   // < 24*16384
  const int p = gid >> 14;
  const int e = gid & (PLANE - 1);
  const int src = (p << 14) | (brev7(e >> 7) << 7) | brev7(e & 127);
  const float m = mags[src] * (1.0f / 16384.0f);
  float sn, cs;
  __sincosf(phases[src], &sn, &cs);
  psi[gid] = make_float2(m * cs, m * sn);
}

// K1: per image: s0 mean + forward fft2 -> Xf (bitrev-domain), packed natural e index.
__global__ __launch_bounds__(NT) void k_img_fft(const float* __restrict__ img,
                                                float2* __restrict__ Xf,
                                                float* __restrict__ s0) {
  __shared__ float sRe[SDIM * PITCH];
  __shared__ float sIm[SDIM * PITCH];
  __shared__ float twR[64], twI[64], red[16];
  const int tid = threadIdx.x;
  const int b = blockIdx.x;
  init_twiddles(twR, twI, tid);
  const float* ip = img + b * PLANE;
  float sum = 0.0f;
#pragma unroll
  for (int k = 0; k < EPT; ++k) {
    const int e = tid + k * NT;
    const int a = (e >> 7) * PITCH + (e & 127);
    const float v = ip[e];
    sRe[a] = v; sIm[a] = 0.0f;
    sum += v;
  }
  const float tot = block_reduce_sum(sum, red, tid);
  if (tid == 0) s0[b] = tot * (1.0f / 16384.0f);
  fft_stages(sRe, sIm, twR, twI, tid, true, false);   // row DIF
  fft_stages(sRe, sIm, twR, twI, tid, false, false);  // col DIF
  __syncthreads();
  float2* xp = Xf + b * PLANE;
#pragma unroll
  for (int k = 0; k < EPT; ++k) {
    const int e = tid + k * NT;
    const int a = (e >> 7) * PITCH + (e & 127);
    xp[e] = make_float2(sRe[a], sIm[a]);
  }
}

// K2: s1 for j=5 only (no second-order usage). One wg per (b, l).
__global__ __launch_bounds__(NT) void k_s1_j5(const float2* __restrict__ Xf,
                                              const float2* __restrict__ psi,
                                              float* __restrict__ s1num) {
  __shared__ float sRe[SDIM * PITCH];
  __shared__ float sIm[SDIM * PITCH];
  __shared__ float twR[64], twI[64], red[16];
  const int tid = threadIdx.x;
  const int b = blockIdx.x >> 2;
  const int l = blockIdx.x & 3;
  init_twiddles(twR, twI, tid);
  const float2* xp = Xf + b * PLANE;
  const float2* pp = psi + (5 * 4 + l) * PLANE;
#pragma unroll
  for (int k = 0; k < EPT; ++k) {
    const int e = tid + k * NT;
    const int a = (e >> 7) * PITCH + (e & 127);
    const float2 x = xp[e];
    const float2 p = pp[e];
    sRe[a] = x.x * p.x - x.y * p.y;
    sIm[a] = x.x * p.y + x.y * p.x;
  }
  fft_stages(sRe, sIm, twR, twI, tid, false, true);   // col DIT
  fft_stages(sRe, sIm, twR, twI, tid, true, true);    // row DIT
  __syncthreads();
  float s = 0.0f;
#pragma unroll
  for (int k = 0; k < EPT; ++k) {
    const int e = tid + k * NT;
    const int a = (e >> 7) * PITCH + (e & 127);
    const float re = sRe[a], im = sIm[a];
    s += sqrtf(re * re + im * im);
  }
  const float tot = block_reduce_sum(s, red, tid);
  if (tid == 0) atomicAdd(&s1num[b * 6 + 5], tot);
}

// K3: one wg per (b, l1, pair(j1,j2)). Uniform work: 2 fft2 + 4 ifft2 per wg.
__global__ __launch_bounds__(NT) void k_s2(const float2* __restrict__ Xf,
                                           const float2* __restrict__ psi,
                                           float* __restrict__ s1num,
                                           float* __restrict__ s2num) {
  __shared__ float sRe[SDIM * PITCH];
  __shared__ float sIm[SDIM * PITCH];
  __shared__ float twR[64], twI[64], red[16];
  const int tid = threadIdx.x;
  const int bid = blockIdx.x;
  const int b = bid / 60;
  const int rem = bid % 60;
  const int l1 = rem / 15;
  const int pair = rem % 15;
  int j1 = 0, base = 0;
  if (pair >= 14)      { j1 = 4; base = 14; }
  else if (pair >= 12) { j1 = 3; base = 12; }
  else if (pair >= 9)  { j1 = 2; base = 9; }
  else if (pair >= 5)  { j1 = 1; base = 5; }
  const int j2 = j1 + 1 + (pair - base);
  init_twiddles(twR, twI, tid);

  // product Xf * psi1 (both in bitrev domain)
  const float2* xp = Xf + b * PLANE;
  const float2* p1 = psi + (j1 * 4 + l1) * PLANE;
#pragma unroll
  for (int k = 0; k < EPT; ++k) {
    const int e = tid + k * NT;
    const int a = (e >> 7) * PITCH + (e & 127);
    const float2 x = xp[e];
    const float2 p = p1[e];
    sRe[a] = x.x * p.x - x.y * p.y;
    sIm[a] = x.x * p.y + x.y * p.x;
  }
  // ifft2 -> u1 (natural order)
  fft_stages(sRe, sIm, twR, twI, tid, false, true);
  fft_stages(sRe, sIm, twR, twI, tid, true, true);
  __syncthreads();
  float s1sum = 0.0f;
#pragma unroll
  for (int k = 0; k < EPT; ++k) {
    const int e = tid + k * NT;
    const int a = (e >> 7) * PITCH + (e & 127);
    const float re = sRe[a], im = sIm[a];
    const float m = sqrtf(re * re + im * im);
    sRe[a] = m; sIm[a] = 0.0f;       // same thread owns this element: no barrier needed
    s1sum += m;
  }
  // forward fft2 of u1 -> U (bitrev domain); internal barrier covers the writes above
  fft_stages(sRe, sIm, twR, twI, tid, true, false);
  fft_stages(sRe, sIm, twR, twI, tid, false, false);
  __syncthreads();
  float Ur[EPT], Ui[EPT];
#pragma unroll
  for (int k = 0; k < EPT; ++k) {
    const int e = tid + k * NT;
    const int a = (e >> 7) * PITCH + (e & 127);
    Ur[k] = sRe[a]; Ui[k] = sIm[a];
  }
  if (j2 == j1 + 1) {                 // block-uniform: fold s1 in exactly once per (b,j1,l1)
    const float tot = block_reduce_sum(s1sum, red, tid);
    if (tid == 0) atomicAdd(&s1num[b * 6 + j1], tot);
  }
  for (int l2 = 0; l2 < 4; ++l2) {
    const float2* p2 = psi + (j2 * 4 + l2) * PLANE;
    __syncthreads();                  // Ur copy / prior reads done before overwrite
#pragma unroll
    for (int k = 0; k < EPT; ++k) {
      const int e = tid + k * NT;
      const int a = (e >> 7) * PITCH + (e & 127);
      const float2 p = p2[e];
      sRe[a] = Ur[k] * p.x - Ui[k] * p.y;
      sIm[a] = Ur[k] * p.y + Ui[k] * p.x;
    }
    fft_stages(sRe, sIm, twR, twI, tid, false, true);
    fft_stages(sRe, sIm, twR, twI, tid, true, true);
    __syncthreads();
    float vs = 0.0f;
#pragma unroll
    for (int k = 0; k < EPT; ++k) {
      const int e = tid + k * NT;
      const int a = (e >> 7) * PITCH + (e & 127);
      const float re = sRe[a], im = sIm[a];
      vs += sqrtf(re * re + im * im);
    }
    const float tot = block_reduce_sum(vs, red, tid);
    if (tid == 0) atomicAdd(&s2num[b * 15 + pair], tot);
  }
}

// K4: assemble features + MLP + sigmoid. One thread per batch element.
__global__ __launch_bounds__(64) void k_final(const float* __restrict__ s0,
                                              const float* __restrict__ s1num,
                                              const float* __restrict__ s2num,
                                              const float* __restrict__ w1,
                                              const float* __restrict__ b1,
                                              const float* __restrict__ w2,
                                              const float* __restrict__ b2,
                                              const float* __restrict__ w3,
                                              const float* __restrict__ b3,
                                              float* __restrict__ out) {
  const int b = threadIdx.x;
  if (b >= 64) return;
  float x[22];
  x[0] = s0[b];
#pragma unroll
  for (int j = 0; j < 6; ++j) x[1 + j] = s1num[b * 6 + j] * (1.0f / (4.0f * 16384.0f));
#pragma unroll
  for (int p = 0; p < 15; ++p) x[7 + p] = s2num[b * 15 + p] * (1.0f / (16.0f * 16384.0f));
  float h1[16];
#pragma unroll
  for (int o = 0; o < 16; ++o) {
    float t = b1[o];
    for (int i = 0; i < 22; ++i) t += x[i] * w1[i * 16 + o];
    h1[o] = fmaxf(t, 0.0f);
  }
  float h2[16];
#pragma unroll
  for (int o = 0; o < 16; ++o) {
    float t = b2[o];
    for (int i = 0; i < 16; ++i) t += h1[i] * w2[i * 16 + o];
    h2[o] = fmaxf(t, 0.0f);
  }
  float t = b3[0];
#pragma unroll
  for (int i = 0; i < 16; ++i) t += h2[i] * w3[i];
  out[b] = 1.0f / (1.0f + expf(-t));
}

extern "C" void kernel_launch(void* const* d_in, const int* in_sizes, int n_in,
                              void* d_out, int out_size, void* d_ws, size_t ws_size,
                              hipStream_t stream) {
  (void)in_sizes; (void)n_in; (void)out_size; (void)ws_size;
  const float* image  = (const float*)d_in[0];
  const float* mags   = (const float*)d_in[1];
  const float* phases = (const float*)d_in[2];
  const float* w1 = (const float*)d_in[3];
  const float* b1 = (const float*)d_in[4];
  const float* w2 = (const float*)d_in[5];
  const float* b2 = (const float*)d_in[6];
  const float* w3 = (const float*)d_in[7];
  const float* b3 = (const float*)d_in[8];
  float* out = (float*)d_out;

  char* ws = (char*)d_ws;
  float2* psi = (float2*)ws;                              // 24*16384*8 = 3,145,728 B
  float2* Xf  = (float2*)(ws + 3145728);                  // 64*16384*8 = 8,388,608 B
  float*  s0  = (float*)(ws + 3145728 + 8388608);         // 64 floats
  float*  s1n = s0 + 64;                                  // 384 floats
  float*  s2n = s1n + 384;                                // 960 floats

  hipMemsetAsync(s1n, 0, (384 + 960) * sizeof(float), stream);
  k_psi<<<dim3(1536), dim3(256), 0, stream>>>(mags, phases, psi);
  k_img_fft<<<dim3(64), dim3(NT), 0, stream>>>(image, Xf, s0);
  k_s1_j5<<<dim3(256), dim3(NT), 0, stream>>>(Xf, psi, s1n);
  k_s2<<<dim3(3840), dim3(NT), 0, stream>>>(Xf, psi, s1n, s2n);
  k_final<<<dim3(1), dim3(64), 0, stream>>>(s0, s1n, s2n, w1, b1, w2, b2, w3, b3, out);
}

// Round 2
// 1740.916 us; speedup vs baseline: 1.6278x; 1.6278x over previous
//
#include <hip/hip_runtime.h>
#include <math.h>

// Scattering net: four-step register FFT (128 = 16 reg-DFT x 8 cross-group DFT).
// Thread (g=tid>>7, q=tid&127) owns 16 elements x[q][g+8m] of each line.
// Spectral storage permutation per axis: k = k1 + 16*k2  ->  position p = 8*k1 + k2.
// psi is pre-permuted into this layout (both axes) with the 1/16384 ifft scale folded in.
// LDS: split re/im planes, pitch 129 (row-pass lane stride 129 -> 2-way bank = free;
// col-pass lane stride 1 -> conflict-free). 4 barriers per fft2 (vs 14 for radix-2-in-LDS).

#define SDIM 128
#define PLANE 16384
#define PITCH 129
#define NT 1024
#define TWO_PI 6.28318530717958647692f

constexpr float W16R[8] = {1.f, 0.9238795325f, 0.7071067812f, 0.3826834324f,
                           0.f, -0.3826834324f, -0.7071067812f, -0.9238795325f};
constexpr float W16I[8] = {0.f, -0.3826834324f, -0.7071067812f, -0.9238795325f,
                           -1.f, -0.9238795325f, -0.7071067812f, -0.3826834324f};
constexpr float W8R[4] = {1.f, 0.7071067812f, 0.f, -0.7071067812f};
constexpr float W8I[4] = {0.f, -0.7071067812f, -1.f, -0.7071067812f};

#define CSWAP(re, im, a, b) { float _t = re[a]; re[a]=re[b]; re[b]=_t; _t = im[a]; im[a]=im[b]; im[b]=_t; }

// out[k] = sum_m in[m] * W16^{+-m*k} (unscaled; INV = conjugated twiddles)
template<bool INV>
__device__ __forceinline__ void dft16(float* re, float* im) {
  CSWAP(re, im, 1, 8) CSWAP(re, im, 2, 4) CSWAP(re, im, 3, 12)
  CSWAP(re, im, 5, 10) CSWAP(re, im, 7, 14) CSWAP(re, im, 11, 13)
#pragma unroll
  for (int ls = 1; ls <= 4; ++ls) {
    const int len = 1 << ls, half = len >> 1, tstep = 16 >> ls;
#pragma unroll
    for (int blk = 0; blk < 16; blk += len) {
#pragma unroll
      for (int j = 0; j < half; ++j) {
        const float wr = W16R[j * tstep];
        const float wi = INV ? -W16I[j * tstep] : W16I[j * tstep];
        const int i1 = blk + j, i2 = i1 + half;
        const float tr = re[i2] * wr - im[i2] * wi;
        const float ti = re[i2] * wi + im[i2] * wr;
        re[i2] = re[i1] - tr; im[i2] = im[i1] - ti;
        re[i1] += tr;         im[i1] += ti;
      }
    }
  }
}

template<bool INV>
__device__ __forceinline__ void dft8(float* re, float* im) {
  CSWAP(re, im, 1, 4) CSWAP(re, im, 3, 6)
#pragma unroll
  for (int ls = 1; ls <= 3; ++ls) {
    const int len = 1 << ls, half = len >> 1, tstep = 8 >> ls;
#pragma unroll
    for (int blk = 0; blk < 8; blk += len) {
#pragma unroll
      for (int j = 0; j < half; ++j) {
        const float wr = W8R[j * tstep];
        const float wi = INV ? -W8I[j * tstep] : W8I[j * tstep];
        const int i1 = blk + j, i2 = i1 + half;
        const float tr = re[i2] * wr - im[i2] * wi;
        const float ti = re[i2] * wi + im[i2] * wr;
        re[i2] = re[i1] - tr; im[i2] = im[i1] - ti;
        re[i1] += tr;         im[i1] += ti;
      }
    }
  }
}

// Forward fft2. In: x regs, R[m] = row q element (g+8m), I = imag.
// Out: col-spectral U regs: R[k2] <-> plane pos (16g+k2, q), R[8+k2] <-> (16g+8+k2, q).
__device__ __forceinline__ void fwd_fft2(float* R, float* I,
                                         float* sRe, float* sIm,
                                         int g, int q,
                                         const float* twr, const float* twi) {
  const int rb = q * PITCH;
  dft16<false>(R, I);
#pragma unroll
  for (int k = 0; k < 16; ++k) {
    const float r = R[k] * twr[k] - I[k] * twi[k];
    I[k] = R[k] * twi[k] + I[k] * twr[k]; R[k] = r;
  }
  __syncthreads();                             // B0: others' prior reads done
#pragma unroll
  for (int k = 0; k < 16; ++k) { const int a = rb + 8 * k + g; sRe[a] = R[k]; sIm[a] = I[k]; }
  __syncthreads();                             // B1
#pragma unroll
  for (int t = 0; t < 8; ++t) {
    const int a1 = rb + 16 * g + t, a2 = a1 + 8;
    R[t] = sRe[a1]; I[t] = sIm[a1]; R[8 + t] = sRe[a2]; I[8 + t] = sIm[a2];
  }
  dft8<false>(R, I); dft8<false>(R + 8, I + 8);
  // write-back hits exactly the cells this thread just read: no barrier
#pragma unroll
  for (int k2 = 0; k2 < 8; ++k2) {
    const int a1 = rb + 16 * g + k2, a2 = a1 + 8;
    sRe[a1] = R[k2]; sIm[a1] = I[k2]; sRe[a2] = R[8 + k2]; sIm[a2] = I[8 + k2];
  }
  __syncthreads();                             // B2: row-spectra complete
  const int c = q;
#pragma unroll
  for (int m = 0; m < 16; ++m) { const int a = (g + 8 * m) * PITCH + c; R[m] = sRe[a]; I[m] = sIm[a]; }
  dft16<false>(R, I);
#pragma unroll
  for (int k = 0; k < 16; ++k) {
    const float r = R[k] * twr[k] - I[k] * twi[k];
    I[k] = R[k] * twi[k] + I[k] * twr[k]; R[k] = r;
  }
  // same cells as the reads above (rows == g mod 8): no barrier
#pragma unroll
  for (int k = 0; k < 16; ++k) { const int a = (8 * k + g) * PITCH + c; sRe[a] = R[k]; sIm[a] = I[k]; }
  __syncthreads();                             // B3
#pragma unroll
  for (int t = 0; t < 8; ++t) {
    const int a1 = (16 * g + t) * PITCH + c, a2 = a1 + 8 * PITCH;
    R[t] = sRe[a1]; I[t] = sIm[a1]; R[8 + t] = sRe[a2]; I[8 + t] = sIm[a2];
  }
  dft8<false>(R, I); dft8<false>(R + 8, I + 8);
}

// Inverse fft2 (unscaled: = 16384 * ifft2; psi carries 1/16384).
// In: col-spectral regs (same layout as fwd_fft2 output). Out: x regs, R[m] = row q elem (g+8m).
__device__ __forceinline__ void inv_fft2(float* R, float* I,
                                         float* sRe, float* sIm,
                                         int g, int q,
                                         const float* twr, const float* twi) {
  const int c = q;
  dft8<true>(R, I); dft8<true>(R + 8, I + 8);  // over k2 -> Z_t for k1a=2g, k1b=2g+1
  __syncthreads();                             // B0: prior consumers done
#pragma unroll
  for (int t = 0; t < 8; ++t) {
    const int a1 = (16 * g + t) * PITCH + c, a2 = a1 + 8 * PITCH;
    sRe[a1] = R[t]; sIm[a1] = I[t]; sRe[a2] = R[8 + t]; sIm[a2] = I[8 + t];
  }
  __syncthreads();                             // B1
#pragma unroll
  for (int k = 0; k < 16; ++k) { const int a = (8 * k + g) * PITCH + c; R[k] = sRe[a]; I[k] = sIm[a]; }
#pragma unroll
  for (int k = 0; k < 16; ++k) {               // * conj(w)
    const float r = R[k] * twr[k] + I[k] * twi[k];
    I[k] = I[k] * twr[k] - R[k] * twi[k]; R[k] = r;
  }
  dft16<true>(R, I);                           // -> column elements rows g+8m
  // same cells as reads (rows == g mod 8): no barrier
#pragma unroll
  for (int m = 0; m < 16; ++m) { const int a = (g + 8 * m) * PITCH + c; sRe[a] = R[m]; sIm[a] = I[m]; }
  __syncthreads();                             // B2: row-spectra ready
  const int rb = q * PITCH;
#pragma unroll
  for (int k2 = 0; k2 < 8; ++k2) {
    const int a1 = rb + 16 * g + k2, a2 = a1 + 8;
    R[k2] = sRe[a1]; I[k2] = sIm[a1]; R[8 + k2] = sRe[a2]; I[8 + k2] = sIm[a2];
  }
  dft8<true>(R, I); dft8<true>(R + 8, I + 8);
  // same cells: no barrier
#pragma unroll
  for (int t = 0; t < 8; ++t) {
    const int a1 = rb + 16 * g + t, a2 = a1 + 8;
    sRe[a1] = R[t]; sIm[a1] = I[t]; sRe[a2] = R[8 + t]; sIm[a2] = I[8 + t];
  }
  __syncthreads();                             // B3
#pragma unroll
  for (int k = 0; k < 16; ++k) { const int a = rb + 8 * k + g; R[k] = sRe[a]; I[k] = sIm[a]; }
#pragma unroll
  for (int k = 0; k < 16; ++k) {               // * conj(w)
    const float r = R[k] * twr[k] + I[k] * twi[k];
    I[k] = I[k] * twr[k] - R[k] * twi[k]; R[k] = r;
  }
  dft16<true>(R, I);                           // -> x[q][g+8m] in regs
}

__device__ __forceinline__ float block_reduce_sum(float v, float* red, int tid) {
#pragma unroll
  for (int o = 32; o > 0; o >>= 1) v += __shfl_down(v, o);
  __syncthreads();
  if ((tid & 63) == 0) red[tid >> 6] = v;
  __syncthreads();
  float t = 0.0f;
  if (tid == 0) {
#pragma unroll
    for (int w = 0; w < 16; ++w) t += red[w];
  }
  return t;
}

__device__ __forceinline__ void init_tw(float* twr, float* twi, int g) {
  const float base = -TWO_PI * (float)g * (1.0f / 128.0f);
#pragma unroll
  for (int k = 0; k < 16; ++k) {
    float sn, cs;
    __sincosf(base * (float)k, &sn, &cs);
    twr[k] = cs; twi[k] = sn;
  }
}

// psi in sigma x sigma spectral-position layout, 1/16384 folded in.
__global__ __launch_bounds__(256) void k_psi(const float* __restrict__ mags,
                                             const float* __restrict__ phases,
                                             float2* __restrict__ psi) {
  const int gid = blockIdx.x * 256 + threadIdx.x;      // < 24*16384
  const int p = gid >> 14;
  const int pos = gid & (PLANE - 1);
  const int pr = pos >> 7, pc = pos & 127;
  const int kr = (pr >> 3) + 16 * (pr & 7);            // sigma^-1
  const int kc = (pc >> 3) + 16 * (pc & 7);
  const int src = (p << 14) + kr * SDIM + kc;
  const float m = mags[src] * (1.0f / 16384.0f);
  float sn, cs;
  __sincosf(phases[src], &sn, &cs);
  psi[gid] = make_float2(m * cs, m * sn);
}

__global__ __launch_bounds__(NT) void k_img_fft(const float* __restrict__ img,
                                                float2* __restrict__ Xf,
                                                float* __restrict__ s0) {
  __shared__ float sRe[SDIM * PITCH];
  __shared__ float sIm[SDIM * PITCH];
  __shared__ float red[16];
  const int tid = threadIdx.x, b = blockIdx.x;
  const int g = tid >> 7, q = tid & 127;
  float twr[16], twi[16];
  init_tw(twr, twi, g);
  const float* ip = img + b * PLANE;
  float sum = 0.0f;
#pragma unroll
  for (int kk = 0; kk < 16; ++kk) {
    const int e = tid + kk * NT;
    const float v = ip[e];
    sRe[(e >> 7) * PITCH + (e & 127)] = v;
    sum += v;
  }
  const float tot = block_reduce_sum(sum, red, tid);   // internal syncs publish sRe
  if (tid == 0) s0[b] = tot * (1.0f / 16384.0f);
  __syncthreads();
  float R[16], I[16];
#pragma unroll
  for (int m = 0; m < 16; ++m) { R[m] = sRe[q * PITCH + g + 8 * m]; I[m] = 0.0f; }
  fwd_fft2(R, I, sRe, sIm, g, q, twr, twi);
  float2* xp = Xf + b * PLANE;
#pragma unroll
  for (int k2 = 0; k2 < 8; ++k2) {
    const int p1 = (16 * g + k2) * SDIM + q;
    const int p2 = p1 + 8 * SDIM;
    xp[p1] = make_float2(R[k2], I[k2]);
    xp[p2] = make_float2(R[8 + k2], I[8 + k2]);
  }
}

// bid < 1280: (j1 = bid>>8 [heavy-first], b = (bid&255)>>2, l1 = bid&3):
//   u1 = |ifft2(Xf . psi1)| once; U = fft2(u1) kept in regs; loop (j2,l2) inner iffts.
// bid >= 1280: s1 for j=5 only.
__global__ __launch_bounds__(NT) void k_scat(const float2* __restrict__ Xf,
                                             const float2* __restrict__ psi,
                                             float* __restrict__ s1num,
                                             float* __restrict__ s2num) {
  __shared__ float sRe[SDIM * PITCH];
  __shared__ float sIm[SDIM * PITCH];
  __shared__ float red[16];
  const int tid = threadIdx.x;
  const int g = tid >> 7, q = tid & 127;
  float twr[16], twi[16];
  init_tw(twr, twi, g);
  const int bid = blockIdx.x;
  float R[16], I[16];

  if (bid < 1280) {
    const int j1 = bid >> 8;
    const int b = (bid & 255) >> 2;
    const int l1 = bid & 3;
    const float2* xp = Xf + b * PLANE;
    const float2* pp = psi + (j1 * 4 + l1) * PLANE;
#pragma unroll
    for (int k2 = 0; k2 < 8; ++k2) {
      const int p1 = (16 * g + k2) * SDIM + q;
      const int p2 = p1 + 8 * SDIM;
      const float2 x1 = xp[p1], v1 = pp[p1];
      const float2 x2 = xp[p2], v2 = pp[p2];
      R[k2] = x1.x * v1.x - x1.y * v1.y;     I[k2] = x1.x * v1.y + x1.y * v1.x;
      R[8 + k2] = x2.x * v2.x - x2.y * v2.y; I[8 + k2] = x2.x * v2.y + x2.y * v2.x;
    }
    inv_fft2(R, I, sRe, sIm, g, q, twr, twi);
    float s1sum = 0.0f;
#pragma unroll
    for (int m = 0; m < 16; ++m) {
      const float a = sqrtf(R[m] * R[m] + I[m] * I[m]);
      s1sum += a; R[m] = a; I[m] = 0.0f;
    }
    fwd_fft2(R, I, sRe, sIm, g, q, twr, twi);
    float Ur[16], Ui[16];
#pragma unroll
    for (int k = 0; k < 16; ++k) { Ur[k] = R[k]; Ui[k] = I[k]; }
    {
      const float tot = block_reduce_sum(s1sum, red, tid);
      if (tid == 0) atomicAdd(&s1num[b * 6 + j1], tot);
    }
    const int pb = (j1 * (11 - j1)) >> 1;    // 0,5,9,12,14
#pragma unroll 1
    for (int j2 = j1 + 1; j2 <= 5; ++j2) {
      float vsum = 0.0f;
#pragma unroll 1
      for (int l2 = 0; l2 < 4; ++l2) {
        const float2* p2p = psi + (j2 * 4 + l2) * PLANE;
#pragma unroll
        for (int k2 = 0; k2 < 8; ++k2) {
          const int p1 = (16 * g + k2) * SDIM + q;
          const int p2i = p1 + 8 * SDIM;
          const float2 v1 = p2p[p1], v2 = p2p[p2i];
          R[k2] = Ur[k2] * v1.x - Ui[k2] * v1.y;
          I[k2] = Ur[k2] * v1.y + Ui[k2] * v1.x;
          R[8 + k2] = Ur[8 + k2] * v2.x - Ui[8 + k2] * v2.y;
          I[8 + k2] = Ur[8 + k2] * v2.y + Ui[8 + k2] * v2.x;
        }
        inv_fft2(R, I, sRe, sIm, g, q, twr, twi);
#pragma unroll
        for (int m = 0; m < 16; ++m) vsum += sqrtf(R[m] * R[m] + I[m] * I[m]);
      }
      const float tot = block_reduce_sum(vsum, red, tid);
      if (tid == 0) atomicAdd(&s2num[b * 15 + pb + (j2 - j1 - 1)], tot);
    }
  } else {
    const int idx = bid - 1280;
    const int b = idx >> 2, l = idx & 3;
    const float2* xp = Xf + b * PLANE;
    const float2* pp = psi + (20 + l) * PLANE;
#pragma unroll
    for (int k2 = 0; k2 < 8; ++k2) {
      const int p1 = (16 * g + k2) * SDIM + q;
      const int p2 = p1 + 8 * SDIM;
      const float2 x1 = xp[p1], v1 = pp[p1];
      const float2 x2 = xp[p2], v2 = pp[p2];
      R[k2] = x1.x * v1.x - x1.y * v1.y;     I[k2] = x1.x * v1.y + x1.y * v1.x;
      R[8 + k2] = x2.x * v2.x - x2.y * v2.y; I[8 + k2] = x2.x * v2.y + x2.y * v2.x;
    }
    inv_fft2(R, I, sRe, sIm, g, q, twr, twi);
    float s = 0.0f;
#pragma unroll
    for (int m = 0; m < 16; ++m) s += sqrtf(R[m] * R[m] + I[m] * I[m]);
    const float tot = block_reduce_sum(s, red, tid);
    if (tid == 0) atomicAdd(&s1num[b * 6 + 5], tot);
  }
}

__global__ __launch_bounds__(64) void k_final(const float* __restrict__ s0,
                                              const float* __restrict__ s1num,
                                              const float* __restrict__ s2num,
                                              const float* __restrict__ w1,
                                              const float* __restrict__ b1,
                                              const float* __restrict__ w2,
                                              const float* __restrict__ b2,
                                              const float* __restrict__ w3,
                                              const float* __restrict__ b3,
                                              float* __restrict__ out) {
  const int b = threadIdx.x;
  if (b >= 64) return;
  float x[22];
  x[0] = s0[b];
#pragma unroll
  for (int j = 0; j < 6; ++j) x[1 + j] = s1num[b * 6 + j] * (1.0f / (4.0f * 16384.0f));
#pragma unroll
  for (int p = 0; p < 15; ++p) x[7 + p] = s2num[b * 15 + p] * (1.0f / (16.0f * 16384.0f));
  float h1[16];
#pragma unroll
  for (int o = 0; o < 16; ++o) {
    float t = b1[o];
    for (int i = 0; i < 22; ++i) t += x[i] * w1[i * 16 + o];
    h1[o] = fmaxf(t, 0.0f);
  }
  float h2[16];
#pragma unroll
  for (int o = 0; o < 16; ++o) {
    float t = b2[o];
    for (int i = 0; i < 16; ++i) t += h1[i] * w2[i * 16 + o];
    h2[o] = fmaxf(t, 0.0f);
  }
  float t = b3[0];
#pragma unroll
  for (int i = 0; i < 16; ++i) t += h2[i] * w3[i];
  out[b] = 1.0f / (1.0f + expf(-t));
}

extern "C" void kernel_launch(void* const* d_in, const int* in_sizes, int n_in,
                              void* d_out, int out_size, void* d_ws, size_t ws_size,
                              hipStream_t stream) {
  (void)in_sizes; (void)n_in; (void)out_size; (void)ws_size;
  const float* image  = (const float*)d_in[0];
  const float* mags   = (const float*)d_in[1];
  const float* phases = (const float*)d_in[2];
  const float* w1 = (const float*)d_in[3];
  const float* b1 = (const float*)d_in[4];
  const float* w2 = (const float*)d_in[5];
  const float* b2 = (const float*)d_in[6];
  const float* w3 = (const float*)d_in[7];
  const float* b3 = (const float*)d_in[8];
  float* out = (float*)d_out;

  char* ws = (char*)d_ws;
  float2* psi = (float2*)ws;                       // 24*16384*8 = 3,145,728 B
  float2* Xf  = (float2*)(ws + 3145728);           // 64*16384*8 = 8,388,608 B
  float*  s0  = (float*)(ws + 3145728 + 8388608);  // 64
  float*  s1n = s0 + 64;                           // 384
  float*  s2n = s1n + 384;                         // 960

  hipMemsetAsync(s1n, 0, (384 + 960) * sizeof(float), stream);
  k_psi<<<dim3(1536), dim3(256), 0, stream>>>(mags, phases, psi);
  k_img_fft<<<dim3(64), dim3(NT), 0, stream>>>(image, Xf, s0);
  k_scat<<<dim3(1536), dim3(NT), 0, stream>>>(Xf, psi, s1n, s2n);
  k_final<<<dim3(1), dim3(64), 0, stream>>>(s0, s1n, s2n, w1, b1, w2, b2, w3, b3, out);
}

// Round 3
// 836.501 us; speedup vs baseline: 3.3877x; 2.0812x over previous
//
#include <hip/hip_runtime.h>
#include <math.h>

// Scattering net: four-step register FFT (128 = 16 reg-DFT x 8 cross-group DFT).
// Thread (g=tid>>7, q=tid&127) owns 16 elements x[q][g+8m] of each line.
// Spectral storage permutation per axis: k = k1 + 16*k2  ->  position p = 8*k1 + k2.
// psi is pre-permuted into this layout (both axes) with the 1/16384 ifft scale folded in.
// LDS: split re/im planes, pitch 129. Twiddle table w128^{g*k} lives in LDS
// (g is wave-uniform -> broadcast reads), freeing 32 VGPRs.
// __launch_bounds__(1024,4): LDS already limits to 1 block/CU (4 waves/EU), so
// declare it -> VGPR cap 128 -> no scratch spills (round-2 failure mode: cap 64,
// ~2.3 GB/dispatch spill traffic thrashing L2).

#define SDIM 128
#define PLANE 16384
#define PITCH 129
#define NT 1024
#define TWO_PI 6.28318530717958647692f

constexpr float W16R[8] = {1.f, 0.9238795325f, 0.7071067812f, 0.3826834324f,
                           0.f, -0.3826834324f, -0.7071067812f, -0.9238795325f};
constexpr float W16I[8] = {0.f, -0.3826834324f, -0.7071067812f, -0.9238795325f,
                           -1.f, -0.9238795325f, -0.7071067812f, -0.3826834324f};
constexpr float W8R[4] = {1.f, 0.7071067812f, 0.f, -0.7071067812f};
constexpr float W8I[4] = {0.f, -0.7071067812f, -1.f, -0.7071067812f};

#define CSWAP(re, im, a, b) { float _t = re[a]; re[a]=re[b]; re[b]=_t; _t = im[a]; im[a]=im[b]; im[b]=_t; }

template<bool INV>
__device__ __forceinline__ void dft16(float* re, float* im) {
  CSWAP(re, im, 1, 8) CSWAP(re, im, 2, 4) CSWAP(re, im, 3, 12)
  CSWAP(re, im, 5, 10) CSWAP(re, im, 7, 14) CSWAP(re, im, 11, 13)
#pragma unroll
  for (int ls = 1; ls <= 4; ++ls) {
    const int len = 1 << ls, half = len >> 1, tstep = 16 >> ls;
#pragma unroll
    for (int blk = 0; blk < 16; blk += len) {
#pragma unroll
      for (int j = 0; j < half; ++j) {
        const float wr = W16R[j * tstep];
        const float wi = INV ? -W16I[j * tstep] : W16I[j * tstep];
        const int i1 = blk + j, i2 = i1 + half;
        const float tr = re[i2] * wr - im[i2] * wi;
        const float ti = re[i2] * wi + im[i2] * wr;
        re[i2] = re[i1] - tr; im[i2] = im[i1] - ti;
        re[i1] += tr;         im[i1] += ti;
      }
    }
  }
}

template<bool INV>
__device__ __forceinline__ void dft8(float* re, float* im) {
  CSWAP(re, im, 1, 4) CSWAP(re, im, 3, 6)
#pragma unroll
  for (int ls = 1; ls <= 3; ++ls) {
    const int len = 1 << ls, half = len >> 1, tstep = 8 >> ls;
#pragma unroll
    for (int blk = 0; blk < 8; blk += len) {
#pragma unroll
      for (int j = 0; j < half; ++j) {
        const float wr = W8R[j * tstep];
        const float wi = INV ? -W8I[j * tstep] : W8I[j * tstep];
        const int i1 = blk + j, i2 = i1 + half;
        const float tr = re[i2] * wr - im[i2] * wi;
        const float ti = re[i2] * wi + im[i2] * wr;
        re[i2] = re[i1] - tr; im[i2] = im[i1] - ti;
        re[i1] += tr;         im[i1] += ti;
      }
    }
  }
}

// tw points at sTw + 16*g (LDS, wave-uniform -> broadcast ds_read_b64)
__device__ __forceinline__ void twmul_fwd(float* R, float* I, const float2* tw) {
#pragma unroll
  for (int k = 0; k < 16; ++k) {
    const float2 w = tw[k];
    const float r = R[k] * w.x - I[k] * w.y;
    I[k] = R[k] * w.y + I[k] * w.x; R[k] = r;
  }
}
__device__ __forceinline__ void twmul_inv(float* R, float* I, const float2* tw) {
#pragma unroll
  for (int k = 0; k < 16; ++k) {
    const float2 w = tw[k];
    const float r = R[k] * w.x + I[k] * w.y;
    I[k] = I[k] * w.x - R[k] * w.y; R[k] = r;
  }
}

// Forward fft2. In: x regs, R[m] = row q element (g+8m).
// Out: col-spectral regs: R[k2] <-> plane pos (16g+k2, q), R[8+k2] <-> (16g+8+k2, q).
__device__ __forceinline__ void fwd_fft2(float* R, float* I,
                                         float* sRe, float* sIm,
                                         int g, int q, const float2* tw) {
  const int rb = q * PITCH;
  dft16<false>(R, I);
  twmul_fwd(R, I, tw);
  __syncthreads();                             // B0: others' prior reads done
#pragma unroll
  for (int k = 0; k < 16; ++k) { const int a = rb + 8 * k + g; sRe[a] = R[k]; sIm[a] = I[k]; }
  __syncthreads();                             // B1
#pragma unroll
  for (int t = 0; t < 8; ++t) {
    const int a1 = rb + 16 * g + t, a2 = a1 + 8;
    R[t] = sRe[a1]; I[t] = sIm[a1]; R[8 + t] = sRe[a2]; I[8 + t] = sIm[a2];
  }
  dft8<false>(R, I); dft8<false>(R + 8, I + 8);
#pragma unroll
  for (int k2 = 0; k2 < 8; ++k2) {             // same cells as reads: no barrier
    const int a1 = rb + 16 * g + k2, a2 = a1 + 8;
    sRe[a1] = R[k2]; sIm[a1] = I[k2]; sRe[a2] = R[8 + k2]; sIm[a2] = I[8 + k2];
  }
  __syncthreads();                             // B2: row-spectra complete
  const int c = q;
#pragma unroll
  for (int m = 0; m < 16; ++m) { const int a = (g + 8 * m) * PITCH + c; R[m] = sRe[a]; I[m] = sIm[a]; }
  dft16<false>(R, I);
  twmul_fwd(R, I, tw);
#pragma unroll
  for (int k = 0; k < 16; ++k) { const int a = (8 * k + g) * PITCH + c; sRe[a] = R[k]; sIm[a] = I[k]; }
  __syncthreads();                             // B3
#pragma unroll
  for (int t = 0; t < 8; ++t) {
    const int a1 = (16 * g + t) * PITCH + c, a2 = a1 + 8 * PITCH;
    R[t] = sRe[a1]; I[t] = sIm[a1]; R[8 + t] = sRe[a2]; I[8 + t] = sIm[a2];
  }
  dft8<false>(R, I); dft8<false>(R + 8, I + 8);
}

// Inverse fft2 (unscaled; psi carries 1/16384). In: col-spectral regs.
// Out: x regs, R[m] = row q elem (g+8m).
__device__ __forceinline__ void inv_fft2(float* R, float* I,
                                         float* sRe, float* sIm,
                                         int g, int q, const float2* tw) {
  const int c = q;
  dft8<true>(R, I); dft8<true>(R + 8, I + 8);
  __syncthreads();                             // B0: prior consumers done
#pragma unroll
  for (int t = 0; t < 8; ++t) {
    const int a1 = (16 * g + t) * PITCH + c, a2 = a1 + 8 * PITCH;
    sRe[a1] = R[t]; sIm[a1] = I[t]; sRe[a2] = R[8 + t]; sIm[a2] = I[8 + t];
  }
  __syncthreads();                             // B1
#pragma unroll
  for (int k = 0; k < 16; ++k) { const int a = (8 * k + g) * PITCH + c; R[k] = sRe[a]; I[k] = sIm[a]; }
  twmul_inv(R, I, tw);
  dft16<true>(R, I);
#pragma unroll
  for (int m = 0; m < 16; ++m) { const int a = (g + 8 * m) * PITCH + c; sRe[a] = R[m]; sIm[a] = I[m]; }
  __syncthreads();                             // B2: row-spectra ready
  const int rb = q * PITCH;
#pragma unroll
  for (int k2 = 0; k2 < 8; ++k2) {
    const int a1 = rb + 16 * g + k2, a2 = a1 + 8;
    R[k2] = sRe[a1]; I[k2] = sIm[a1]; R[8 + k2] = sRe[a2]; I[8 + k2] = sIm[a2];
  }
  dft8<true>(R, I); dft8<true>(R + 8, I + 8);
#pragma unroll
  for (int t = 0; t < 8; ++t) {                // same cells: no barrier
    const int a1 = rb + 16 * g + t, a2 = a1 + 8;
    sRe[a1] = R[t]; sIm[a1] = I[t]; sRe[a2] = R[8 + t]; sIm[a2] = I[8 + t];
  }
  __syncthreads();                             // B3
#pragma unroll
  for (int k = 0; k < 16; ++k) { const int a = rb + 8 * k + g; R[k] = sRe[a]; I[k] = sIm[a]; }
  twmul_inv(R, I, tw);
  dft16<true>(R, I);
}

__device__ __forceinline__ float block_reduce_sum(float v, float* red, int tid) {
#pragma unroll
  for (int o = 32; o > 0; o >>= 1) v += __shfl_down(v, o);
  __syncthreads();
  if ((tid & 63) == 0) red[tid >> 6] = v;
  __syncthreads();
  float t = 0.0f;
  if (tid == 0) {
#pragma unroll
    for (int w = 0; w < 16; ++w) t += red[w];
  }
  return t;
}

__device__ __forceinline__ void init_tw_lds(float2* sTw, int tid) {
  if (tid < 128) {
    const int gg = tid >> 4, k = tid & 15;
    float sn, cs;
    __sincosf(-TWO_PI * (float)(gg * k) * (1.0f / 128.0f), &sn, &cs);
    sTw[tid] = make_float2(cs, sn);
  }
}

// psi in sigma x sigma spectral-position layout, 1/16384 folded in.
__global__ __launch_bounds__(256) void k_psi(const float* __restrict__ mags,
                                             const float* __restrict__ phases,
                                             float2* __restrict__ psi) {
  const int gid = blockIdx.x * 256 + threadIdx.x;      // < 24*16384
  const int p = gid >> 14;
  const int pos = gid & (PLANE - 1);
  const int pr = pos >> 7, pc = pos & 127;
  const int kr = (pr >> 3) + 16 * (pr & 7);            // sigma^-1
  const int kc = (pc >> 3) + 16 * (pc & 7);
  const int src = (p << 14) + kr * SDIM + kc;
  const float m = mags[src] * (1.0f / 16384.0f);
  float sn, cs;
  __sincosf(phases[src], &sn, &cs);
  psi[gid] = make_float2(m * cs, m * sn);
}

__global__ __launch_bounds__(NT, 4) void k_img_fft(const float* __restrict__ img,
                                                   float2* __restrict__ Xf,
                                                   float* __restrict__ s0) {
  __shared__ float sRe[SDIM * PITCH];
  __shared__ float sIm[SDIM * PITCH];
  __shared__ float2 sTw[128];
  __shared__ float red[16];
  const int tid = threadIdx.x, b = blockIdx.x;
  const int g = tid >> 7, q = tid & 127;
  init_tw_lds(sTw, tid);
  const float2* tw = sTw + 16 * g;
  const float* ip = img + b * PLANE;
  float sum = 0.0f;
#pragma unroll
  for (int kk = 0; kk < 16; ++kk) {
    const int e = tid + kk * NT;
    const float v = ip[e];
    sRe[(e >> 7) * PITCH + (e & 127)] = v;
    sum += v;
  }
  const float tot = block_reduce_sum(sum, red, tid);   // internal syncs publish sRe & sTw
  if (tid == 0) s0[b] = tot * (1.0f / 16384.0f);
  __syncthreads();
  float R[16], I[16];
#pragma unroll
  for (int m = 0; m < 16; ++m) { R[m] = sRe[q * PITCH + g + 8 * m]; I[m] = 0.0f; }
  fwd_fft2(R, I, sRe, sIm, g, q, tw);
  float2* xp = Xf + b * PLANE;
#pragma unroll
  for (int k2 = 0; k2 < 8; ++k2) {
    const int p1 = (16 * g + k2) * SDIM + q;
    const int p2 = p1 + 8 * SDIM;
    xp[p1] = make_float2(R[k2], I[k2]);
    xp[p2] = make_float2(R[8 + k2], I[8 + k2]);
  }
}

// bid < 1280: (j1 = bid>>8 [heavy-first], b = (bid&255)>>2, l1 = bid&3):
//   u1 = |ifft2(Xf . psi1)| once; U = fft2(u1) in regs; loop (j2,l2) inner iffts.
// bid >= 1280: s1 for j=5 only.
__global__ __launch_bounds__(NT, 4) void k_scat(const float2* __restrict__ Xf,
                                                const float2* __restrict__ psi,
                                                float* __restrict__ s1num,
                                                float* __restrict__ s2num) {
  __shared__ float sRe[SDIM * PITCH];
  __shared__ float sIm[SDIM * PITCH];
  __shared__ float2 sTw[128];
  __shared__ float red[16];
  const int tid = threadIdx.x;
  const int g = tid >> 7, q = tid & 127;
  init_tw_lds(sTw, tid);
  const float2* tw = sTw + 16 * g;
  const int bid = blockIdx.x;
  float R[16], I[16];

  if (bid < 1280) {
    const int j1 = bid >> 8;
    const int b = (bid & 255) >> 2;
    const int l1 = bid & 3;
    const float2* xp = Xf + b * PLANE;
    const float2* pp = psi + (j1 * 4 + l1) * PLANE;
#pragma unroll
    for (int k2 = 0; k2 < 8; ++k2) {
      const int p1 = (16 * g + k2) * SDIM + q;
      const int p2 = p1 + 8 * SDIM;
      const float2 x1 = xp[p1], v1 = pp[p1];
      const float2 x2 = xp[p2], v2 = pp[p2];
      R[k2] = x1.x * v1.x - x1.y * v1.y;     I[k2] = x1.x * v1.y + x1.y * v1.x;
      R[8 + k2] = x2.x * v2.x - x2.y * v2.y; I[8 + k2] = x2.x * v2.y + x2.y * v2.x;
    }
    inv_fft2(R, I, sRe, sIm, g, q, tw);
    float s1sum = 0.0f;
#pragma unroll
    for (int m = 0; m < 16; ++m) {
      const float a = sqrtf(R[m] * R[m] + I[m] * I[m]);
      s1sum += a; R[m] = a; I[m] = 0.0f;
    }
    fwd_fft2(R, I, sRe, sIm, g, q, tw);
    float Ur[16], Ui[16];
#pragma unroll
    for (int k = 0; k < 16; ++k) { Ur[k] = R[k]; Ui[k] = I[k]; }
    {
      const float tot = block_reduce_sum(s1sum, red, tid);
      if (tid == 0) atomicAdd(&s1num[b * 6 + j1], tot);
    }
    const int pb = (j1 * (11 - j1)) >> 1;    // 0,5,9,12,14
#pragma unroll 1
    for (int j2 = j1 + 1; j2 <= 5; ++j2) {
      float vsum = 0.0f;
#pragma unroll 1
      for (int l2 = 0; l2 < 4; ++l2) {
        const float2* p2p = psi + (j2 * 4 + l2) * PLANE;
#pragma unroll
        for (int k2 = 0; k2 < 8; ++k2) {
          const int p1 = (16 * g + k2) * SDIM + q;
          const int p2i = p1 + 8 * SDIM;
          const float2 v1 = p2p[p1], v2 = p2p[p2i];
          R[k2] = Ur[k2] * v1.x - Ui[k2] * v1.y;
          I[k2] = Ur[k2] * v1.y + Ui[k2] * v1.x;
          R[8 + k2] = Ur[8 + k2] * v2.x - Ui[8 + k2] * v2.y;
          I[8 + k2] = Ur[8 + k2] * v2.y + Ui[8 + k2] * v2.x;
        }
        inv_fft2(R, I, sRe, sIm, g, q, tw);
#pragma unroll
        for (int m = 0; m < 16; ++m) vsum += sqrtf(R[m] * R[m] + I[m] * I[m]);
      }
      const float tot = block_reduce_sum(vsum, red, tid);
      if (tid == 0) atomicAdd(&s2num[b * 15 + pb + (j2 - j1 - 1)], tot);
    }
  } else {
    const int idx = bid - 1280;
    const int b = idx >> 2, l = idx & 3;
    const float2* xp = Xf + b * PLANE;
    const float2* pp = psi + (20 + l) * PLANE;
#pragma unroll
    for (int k2 = 0; k2 < 8; ++k2) {
      const int p1 = (16 * g + k2) * SDIM + q;
      const int p2 = p1 + 8 * SDIM;
      const float2 x1 = xp[p1], v1 = pp[p1];
      const float2 x2 = xp[p2], v2 = pp[p2];
      R[k2] = x1.x * v1.x - x1.y * v1.y;     I[k2] = x1.x * v1.y + x1.y * v1.x;
      R[8 + k2] = x2.x * v2.x - x2.y * v2.y; I[8 + k2] = x2.x * v2.y + x2.y * v2.x;
    }
    inv_fft2(R, I, sRe, sIm, g, q, tw);
    float s = 0.0f;
#pragma unroll
    for (int m = 0; m < 16; ++m) s += sqrtf(R[m] * R[m] + I[m] * I[m]);
    const float tot = block_reduce_sum(s, red, tid);
    if (tid == 0) atomicAdd(&s1num[b * 6 + 5], tot);
  }
}

__global__ __launch_bounds__(64) void k_final(const float* __restrict__ s0,
                                              const float* __restrict__ s1num,
                                              const float* __restrict__ s2num,
                                              const float* __restrict__ w1,
                                              const float* __restrict__ b1,
                                              const float* __restrict__ w2,
                                              const float* __restrict__ b2,
                                              const float* __restrict__ w3,
                                              const float* __restrict__ b3,
                                              float* __restrict__ out) {
  const int b = threadIdx.x;
  if (b >= 64) return;
  float x[22];
  x[0] = s0[b];
#pragma unroll
  for (int j = 0; j < 6; ++j) x[1 + j] = s1num[b * 6 + j] * (1.0f / (4.0f * 16384.0f));
#pragma unroll
  for (int p = 0; p < 15; ++p) x[7 + p] = s2num[b * 15 + p] * (1.0f / (16.0f * 16384.0f));
  float h1[16];
#pragma unroll
  for (int o = 0; o < 16; ++o) {
    float t = b1[o];
    for (int i = 0; i < 22; ++i) t += x[i] * w1[i * 16 + o];
    h1[o] = fmaxf(t, 0.0f);
  }
  float h2[16];
#pragma unroll
  for (int o = 0; o < 16; ++o) {
    float t = b2[o];
    for (int i = 0; i < 16; ++i) t += h1[i] * w2[i * 16 + o];
    h2[o] = fmaxf(t, 0.0f);
  }
  float t = b3[0];
#pragma unroll
  for (int i = 0; i < 16; ++i) t += h2[i] * w3[i];
  out[b] = 1.0f / (1.0f + expf(-t));
}

extern "C" void kernel_launch(void* const* d_in, const int* in_sizes, int n_in,
                              void* d_out, int out_size, void* d_ws, size_t ws_size,
                              hipStream_t stream) {
  (void)in_sizes; (void)n_in; (void)out_size; (void)ws_size;
  const float* image  = (const float*)d_in[0];
  const float* mags   = (const float*)d_in[1];
  const float* phases = (const float*)d_in[2];
  const float* w1 = (const float*)d_in[3];
  const float* b1 = (const float*)d_in[4];
  const float* w2 = (const float*)d_in[5];
  const float* b2 = (const float*)d_in[6];
  const float* w3 = (const float*)d_in[7];
  const float* b3 = (const float*)d_in[8];
  float* out = (float*)d_out;

  char* ws = (char*)d_ws;
  float2* psi = (float2*)ws;                       // 24*16384*8 = 3,145,728 B
  float2* Xf  = (float2*)(ws + 3145728);           // 64*16384*8 = 8,388,608 B
  float*  s0  = (float*)(ws + 3145728 + 8388608);  // 64
  float*  s1n = s0 + 64;                           // 384
  float*  s2n = s1n + 384;                         // 960

  hipMemsetAsync(s1n, 0, (384 + 960) * sizeof(float), stream);
  k_psi<<<dim3(1536), dim3(256), 0, stream>>>(mags, phases, psi);
  k_img_fft<<<dim3(64), dim3(NT), 0, stream>>>(image, Xf, s0);
  k_scat<<<dim3(1536), dim3(NT), 0, stream>>>(Xf, psi, s1n, s2n);
  k_final<<<dim3(1), dim3(64), 0, stream>>>(s0, s1n, s2n, w1, b1, w2, b2, w3, b3, out);
}

// Round 4
// 833.145 us; speedup vs baseline: 3.4013x; 1.0040x over previous
//
#include <hip/hip_runtime.h>
#include <math.h>

// Scattering net: four-step register FFT (128 = 16 reg-DFT x 8 cross-group DFT).
// Thread (g=tid>>7, q=tid&127) owns 16 elements x[q][g+8m] of each line.
// Spectral storage permutation per axis: k = k1 + 16*k2  ->  position p = 8*k1 + k2.
// psi is pre-permuted into this layout (both axes) with the 1/16384 ifft scale folded in.
// LDS: split re/im planes, pitch 129 (row-pass lane stride 129 words -> 2-way bank
// aliasing = free; col-pass stride 1 -> conflict-free). Twiddles w128^{gk} in LDS
// (g wave-uniform -> broadcast reads).
// Occupancy pinned with amdgpu_waves_per_eu(4,4): LDS (132 KiB) forces 1 block/CU
// = 4 waves/EU; declaring the exact range raises the VGPR budget to 128 so the
// 64-float live set (R/I + Ur/Ui) does NOT spill. (launch_bounds(1024,4) only set
// a minimum -> allocator still capped at 64 VGPR and spilled ~16 regs: 77 MB/dispatch
// scratch writes in round 3.)

#define SDIM 128
#define PLANE 16384
#define PITCH 129
#define NT 1024
#define TWO_PI 6.28318530717958647692f

#define WG_ATTRS __attribute__((amdgpu_flat_work_group_size(1024, 1024), amdgpu_waves_per_eu(4, 4)))

constexpr float W16R[8] = {1.f, 0.9238795325f, 0.7071067812f, 0.3826834324f,
                           0.f, -0.3826834324f, -0.7071067812f, -0.9238795325f};
constexpr float W16I[8] = {0.f, -0.3826834324f, -0.7071067812f, -0.9238795325f,
                           -1.f, -0.9238795325f, -0.7071067812f, -0.3826834324f};
constexpr float W8R[4] = {1.f, 0.7071067812f, 0.f, -0.7071067812f};
constexpr float W8I[4] = {0.f, -0.7071067812f, -1.f, -0.7071067812f};

#define CSWAP(re, im, a, b) { float _t = re[a]; re[a]=re[b]; re[b]=_t; _t = im[a]; im[a]=im[b]; im[b]=_t; }

template<bool INV>
__device__ __forceinline__ void dft16(float* re, float* im) {
  CSWAP(re, im, 1, 8) CSWAP(re, im, 2, 4) CSWAP(re, im, 3, 12)
  CSWAP(re, im, 5, 10) CSWAP(re, im, 7, 14) CSWAP(re, im, 11, 13)
#pragma unroll
  for (int ls = 1; ls <= 4; ++ls) {
    const int len = 1 << ls, half = len >> 1, tstep = 16 >> ls;
#pragma unroll
    for (int blk = 0; blk < 16; blk += len) {
#pragma unroll
      for (int j = 0; j < half; ++j) {
        const float wr = W16R[j * tstep];
        const float wi = INV ? -W16I[j * tstep] : W16I[j * tstep];
        const int i1 = blk + j, i2 = i1 + half;
        const float tr = re[i2] * wr - im[i2] * wi;
        const float ti = re[i2] * wi + im[i2] * wr;
        re[i2] = re[i1] - tr; im[i2] = im[i1] - ti;
        re[i1] += tr;         im[i1] += ti;
      }
    }
  }
}

template<bool INV>
__device__ __forceinline__ void dft8(float* re, float* im) {
  CSWAP(re, im, 1, 4) CSWAP(re, im, 3, 6)
#pragma unroll
  for (int ls = 1; ls <= 3; ++ls) {
    const int len = 1 << ls, half = len >> 1, tstep = 8 >> ls;
#pragma unroll
    for (int blk = 0; blk < 8; blk += len) {
#pragma unroll
      for (int j = 0; j < half; ++j) {
        const float wr = W8R[j * tstep];
        const float wi = INV ? -W8I[j * tstep] : W8I[j * tstep];
        const int i1 = blk + j, i2 = i1 + half;
        const float tr = re[i2] * wr - im[i2] * wi;
        const float ti = re[i2] * wi + im[i2] * wr;
        re[i2] = re[i1] - tr; im[i2] = im[i1] - ti;
        re[i1] += tr;         im[i1] += ti;
      }
    }
  }
}

// tw points at sTw + 16*g (LDS, wave-uniform -> broadcast ds_read_b64)
__device__ __forceinline__ void twmul_fwd(float* R, float* I, const float2* tw) {
#pragma unroll
  for (int k = 0; k < 16; ++k) {
    const float2 w = tw[k];
    const float r = R[k] * w.x - I[k] * w.y;
    I[k] = R[k] * w.y + I[k] * w.x; R[k] = r;
  }
}
__device__ __forceinline__ void twmul_inv(float* R, float* I, const float2* tw) {
#pragma unroll
  for (int k = 0; k < 16; ++k) {
    const float2 w = tw[k];
    const float r = R[k] * w.x + I[k] * w.y;
    I[k] = I[k] * w.x - R[k] * w.y; R[k] = r;
  }
}

// Forward fft2. In: x regs, R[m] = row q element (g+8m).
// Out: col-spectral regs: R[k2] <-> plane pos (16g+k2, q), R[8+k2] <-> (16g+8+k2, q).
__device__ __forceinline__ void fwd_fft2(float* R, float* I,
                                         float* sRe, float* sIm,
                                         int g, int q, const float2* tw) {
  const int rb = q * PITCH;
  dft16<false>(R, I);
  twmul_fwd(R, I, tw);
  __syncthreads();                             // B0: others' prior reads done
#pragma unroll
  for (int k = 0; k < 16; ++k) { const int a = rb + 8 * k + g; sRe[a] = R[k]; sIm[a] = I[k]; }
  __syncthreads();                             // B1
#pragma unroll
  for (int t = 0; t < 8; ++t) {
    const int a1 = rb + 16 * g + t, a2 = a1 + 8;
    R[t] = sRe[a1]; I[t] = sIm[a1]; R[8 + t] = sRe[a2]; I[8 + t] = sIm[a2];
  }
  dft8<false>(R, I); dft8<false>(R + 8, I + 8);
#pragma unroll
  for (int k2 = 0; k2 < 8; ++k2) {             // same cells as reads: no barrier
    const int a1 = rb + 16 * g + k2, a2 = a1 + 8;
    sRe[a1] = R[k2]; sIm[a1] = I[k2]; sRe[a2] = R[8 + k2]; sIm[a2] = I[8 + k2];
  }
  __syncthreads();                             // B2: row-spectra complete
  const int c = q;
#pragma unroll
  for (int m = 0; m < 16; ++m) { const int a = (g + 8 * m) * PITCH + c; R[m] = sRe[a]; I[m] = sIm[a]; }
  dft16<false>(R, I);
  twmul_fwd(R, I, tw);
#pragma unroll
  for (int k = 0; k < 16; ++k) { const int a = (8 * k + g) * PITCH + c; sRe[a] = R[k]; sIm[a] = I[k]; }
  __syncthreads();                             // B3
#pragma unroll
  for (int t = 0; t < 8; ++t) {
    const int a1 = (16 * g + t) * PITCH + c, a2 = a1 + 8 * PITCH;
    R[t] = sRe[a1]; I[t] = sIm[a1]; R[8 + t] = sRe[a2]; I[8 + t] = sIm[a2];
  }
  dft8<false>(R, I); dft8<false>(R + 8, I + 8);
}

// Inverse fft2 (unscaled; psi carries 1/16384). In: col-spectral regs.
// Out: x regs, R[m] = row q elem (g+8m).
__device__ __forceinline__ void inv_fft2(float* R, float* I,
                                         float* sRe, float* sIm,
                                         int g, int q, const float2* tw) {
  const int c = q;
  dft8<true>(R, I); dft8<true>(R + 8, I + 8);
  __syncthreads();                             // B0: prior consumers done
#pragma unroll
  for (int t = 0; t < 8; ++t) {
    const int a1 = (16 * g + t) * PITCH + c, a2 = a1 + 8 * PITCH;
    sRe[a1] = R[t]; sIm[a1] = I[t]; sRe[a2] = R[8 + t]; sIm[a2] = I[8 + t];
  }
  __syncthreads();                             // B1
#pragma unroll
  for (int k = 0; k < 16; ++k) { const int a = (8 * k + g) * PITCH + c; R[k] = sRe[a]; I[k] = sIm[a]; }
  twmul_inv(R, I, tw);
  dft16<true>(R, I);
#pragma unroll
  for (int m = 0; m < 16; ++m) { const int a = (g + 8 * m) * PITCH + c; sRe[a] = R[m]; sIm[a] = I[m]; }
  __syncthreads();                             // B2: row-spectra ready
  const int rb = q * PITCH;
#pragma unroll
  for (int k2 = 0; k2 < 8; ++k2) {
    const int a1 = rb + 16 * g + k2, a2 = a1 + 8;
    R[k2] = sRe[a1]; I[k2] = sIm[a1]; R[8 + k2] = sRe[a2]; I[8 + k2] = sIm[a2];
  }
  dft8<true>(R, I); dft8<true>(R + 8, I + 8);
#pragma unroll
  for (int t = 0; t < 8; ++t) {                // same cells: no barrier
    const int a1 = rb + 16 * g + t, a2 = a1 + 8;
    sRe[a1] = R[t]; sIm[a1] = I[t]; sRe[a2] = R[8 + t]; sIm[a2] = I[8 + t];
  }
  __syncthreads();                             // B3
#pragma unroll
  for (int k = 0; k < 16; ++k) { const int a = rb + 8 * k + g; R[k] = sRe[a]; I[k] = sIm[a]; }
  twmul_inv(R, I, tw);
  dft16<true>(R, I);
}

__device__ __forceinline__ float block_reduce_sum(float v, float* red, int tid) {
#pragma unroll
  for (int o = 32; o > 0; o >>= 1) v += __shfl_down(v, o);
  __syncthreads();
  if ((tid & 63) == 0) red[tid >> 6] = v;
  __syncthreads();
  float t = 0.0f;
  if (tid == 0) {
#pragma unroll
    for (int w = 0; w < 16; ++w) t += red[w];
  }
  return t;
}

__device__ __forceinline__ void init_tw_lds(float2* sTw, int tid) {
  if (tid < 128) {
    const int gg = tid >> 4, k = tid & 15;
    float sn, cs;
    __sincosf(-TWO_PI * (float)(gg * k) * (1.0f / 128.0f), &sn, &cs);
    sTw[tid] = make_float2(cs, sn);
  }
}

// psi in sigma x sigma spectral-position layout, 1/16384 folded in.
__global__ __launch_bounds__(256) void k_psi(const float* __restrict__ mags,
                                             const float* __restrict__ phases,
                                             float2* __restrict__ psi) {
  const int gid = blockIdx.x * 256 + threadIdx.x;      // < 24*16384
  const int p = gid >> 14;
  const int pos = gid & (PLANE - 1);
  const int pr = pos >> 7, pc = pos & 127;
  const int kr = (pr >> 3) + 16 * (pr & 7);            // sigma^-1
  const int kc = (pc >> 3) + 16 * (pc & 7);
  const int src = (p << 14) + kr * SDIM + kc;
  const float m = mags[src] * (1.0f / 16384.0f);
  float sn, cs;
  __sincosf(phases[src], &sn, &cs);
  psi[gid] = make_float2(m * cs, m * sn);
}

__global__ WG_ATTRS void k_img_fft(const float* __restrict__ img,
                                   float2* __restrict__ Xf,
                                   float* __restrict__ s0) {
  __shared__ float sRe[SDIM * PITCH];
  __shared__ float sIm[SDIM * PITCH];
  __shared__ float2 sTw[128];
  __shared__ float red[16];
  const int tid = threadIdx.x, b = blockIdx.x;
  const int g = tid >> 7, q = tid & 127;
  init_tw_lds(sTw, tid);
  const float2* tw = sTw + 16 * g;
  const float* ip = img + b * PLANE;
  float sum = 0.0f;
#pragma unroll
  for (int kk = 0; kk < 16; ++kk) {
    const int e = tid + kk * NT;
    const float v = ip[e];
    sRe[(e >> 7) * PITCH + (e & 127)] = v;
    sum += v;
  }
  const float tot = block_reduce_sum(sum, red, tid);   // internal syncs publish sRe & sTw
  if (tid == 0) s0[b] = tot * (1.0f / 16384.0f);
  __syncthreads();
  float R[16], I[16];
#pragma unroll
  for (int m = 0; m < 16; ++m) { R[m] = sRe[q * PITCH + g + 8 * m]; I[m] = 0.0f; }
  fwd_fft2(R, I, sRe, sIm, g, q, tw);
  float2* xp = Xf + b * PLANE;
#pragma unroll
  for (int k2 = 0; k2 < 8; ++k2) {
    const int p1 = (16 * g + k2) * SDIM + q;
    const int p2 = p1 + 8 * SDIM;
    xp[p1] = make_float2(R[k2], I[k2]);
    xp[p2] = make_float2(R[8 + k2], I[8 + k2]);
  }
}

// bid < 1280: (j1 = bid>>8 [heavy-first], b = (bid&255)>>2, l1 = bid&3):
//   u1 = |ifft2(Xf . psi1)| once; U = fft2(u1) in regs; loop (j2,l2) inner iffts.
// bid >= 1280: s1 for j=5 only.
// Per-CU balance: 6 block categories (22,18,14,10,6,1 fft2-units) x 256 each = 71 units/CU.
__global__ WG_ATTRS void k_scat(const float2* __restrict__ Xf,
                                const float2* __restrict__ psi,
                                float* __restrict__ s1num,
                                float* __restrict__ s2num) {
  __shared__ float sRe[SDIM * PITCH];
  __shared__ float sIm[SDIM * PITCH];
  __shared__ float2 sTw[128];
  __shared__ float red[16];
  const int tid = threadIdx.x;
  const int g = tid >> 7, q = tid & 127;
  init_tw_lds(sTw, tid);
  const float2* tw = sTw + 16 * g;
  const int bid = blockIdx.x;
  float R[16], I[16];

  if (bid < 1280) {
    const int j1 = bid >> 8;
    const int b = (bid & 255) >> 2;
    const int l1 = bid & 3;
    const float2* xp = Xf + b * PLANE;
    const float2* pp = psi + (j1 * 4 + l1) * PLANE;
#pragma unroll
    for (int k2 = 0; k2 < 8; ++k2) {
      const int p1 = (16 * g + k2) * SDIM + q;
      const int p2 = p1 + 8 * SDIM;
      const float2 x1 = xp[p1], v1 = pp[p1];
      const float2 x2 = xp[p2], v2 = pp[p2];
      R[k2] = x1.x * v1.x - x1.y * v1.y;     I[k2] = x1.x * v1.y + x1.y * v1.x;
      R[8 + k2] = x2.x * v2.x - x2.y * v2.y; I[8 + k2] = x2.x * v2.y + x2.y * v2.x;
    }
    inv_fft2(R, I, sRe, sIm, g, q, tw);
    float s1sum = 0.0f;
#pragma unroll
    for (int m = 0; m < 16; ++m) {
      const float a = sqrtf(R[m] * R[m] + I[m] * I[m]);
      s1sum += a; R[m] = a; I[m] = 0.0f;
    }
    fwd_fft2(R, I, sRe, sIm, g, q, tw);
    float Ur[16], Ui[16];
#pragma unroll
    for (int k = 0; k < 16; ++k) { Ur[k] = R[k]; Ui[k] = I[k]; }
    {
      const float tot = block_reduce_sum(s1sum, red, tid);
      if (tid == 0) atomicAdd(&s1num[b * 6 + j1], tot);
    }
    const int pb = (j1 * (11 - j1)) >> 1;    // 0,5,9,12,14
#pragma unroll 1
    for (int j2 = j1 + 1; j2 <= 5; ++j2) {
      float vsum = 0.0f;
#pragma unroll 1
      for (int l2 = 0; l2 < 4; ++l2) {
        const float2* p2p = psi + (j2 * 4 + l2) * PLANE;
#pragma unroll
        for (int k2 = 0; k2 < 8; ++k2) {
          const int p1 = (16 * g + k2) * SDIM + q;
          const int p2i = p1 + 8 * SDIM;
          const float2 v1 = p2p[p1], v2 = p2p[p2i];
          R[k2] = Ur[k2] * v1.x - Ui[k2] * v1.y;
          I[k2] = Ur[k2] * v1.y + Ui[k2] * v1.x;
          R[8 + k2] = Ur[8 + k2] * v2.x - Ui[8 + k2] * v2.y;
          I[8 + k2] = Ur[8 + k2] * v2.y + Ui[8 + k2] * v2.x;
        }
        inv_fft2(R, I, sRe, sIm, g, q, tw);
#pragma unroll
        for (int m = 0; m < 16; ++m) vsum += sqrtf(R[m] * R[m] + I[m] * I[m]);
      }
      const float tot = block_reduce_sum(vsum, red, tid);
      if (tid == 0) atomicAdd(&s2num[b * 15 + pb + (j2 - j1 - 1)], tot);
    }
  } else {
    const int idx = bid - 1280;
    const int b = idx >> 2, l = idx & 3;
    const float2* xp = Xf + b * PLANE;
    const float2* pp = psi + (20 + l) * PLANE;
#pragma unroll
    for (int k2 = 0; k2 < 8; ++k2) {
      const int p1 = (16 * g + k2) * SDIM + q;
      const int p2 = p1 + 8 * SDIM;
      const float2 x1 = xp[p1], v1 = pp[p1];
      const float2 x2 = xp[p2], v2 = pp[p2];
      R[k2] = x1.x * v1.x - x1.y * v1.y;     I[k2] = x1.x * v1.y + x1.y * v1.x;
      R[8 + k2] = x2.x * v2.x - x2.y * v2.y; I[8 + k2] = x2.x * v2.y + x2.y * v2.x;
    }
    inv_fft2(R, I, sRe, sIm, g, q, tw);
    float s = 0.0f;
#pragma unroll
    for (int m = 0; m < 16; ++m) s += sqrtf(R[m] * R[m] + I[m] * I[m]);
    const float tot = block_reduce_sum(s, red, tid);
    if (tid == 0) atomicAdd(&s1num[b * 6 + 5], tot);
  }
}

__global__ __launch_bounds__(64) void k_final(const float* __restrict__ s0,
                                              const float* __restrict__ s1num,
                                              const float* __restrict__ s2num,
                                              const float* __restrict__ w1,
                                              const float* __restrict__ b1,
                                              const float* __restrict__ w2,
                                              const float* __restrict__ b2,
                                              const float* __restrict__ w3,
                                              const float* __restrict__ b3,
                                              float* __restrict__ out) {
  const int b = threadIdx.x;
  if (b >= 64) return;
  float x[22];
  x[0] = s0[b];
#pragma unroll
  for (int j = 0; j < 6; ++j) x[1 + j] = s1num[b * 6 + j] * (1.0f / (4.0f * 16384.0f));
#pragma unroll
  for (int p = 0; p < 15; ++p) x[7 + p] = s2num[b * 15 + p] * (1.0f / (16.0f * 16384.0f));
  float h1[16];
#pragma unroll
  for (int o = 0; o < 16; ++o) {
    float t = b1[o];
    for (int i = 0; i < 22; ++i) t += x[i] * w1[i * 16 + o];
    h1[o] = fmaxf(t, 0.0f);
  }
  float h2[16];
#pragma unroll
  for (int o = 0; o < 16; ++o) {
    float t = b2[o];
    for (int i = 0; i < 16; ++i) t += h1[i] * w2[i * 16 + o];
    h2[o] = fmaxf(t, 0.0f);
  }
  float t = b3[0];
#pragma unroll
  for (int i = 0; i < 16; ++i) t += h2[i] * w3[i];
  out[b] = 1.0f / (1.0f + expf(-t));
}

extern "C" void kernel_launch(void* const* d_in, const int* in_sizes, int n_in,
                              void* d_out, int out_size, void* d_ws, size_t ws_size,
                              hipStream_t stream) {
  (void)in_sizes; (void)n_in; (void)out_size; (void)ws_size;
  const float* image  = (const float*)d_in[0];
  const float* mags   = (const float*)d_in[1];
  const float* phases = (const float*)d_in[2];
  const float* w1 = (const float*)d_in[3];
  const float* b1 = (const float*)d_in[4];
  const float* w2 = (const float*)d_in[5];
  const float* b2 = (const float*)d_in[6];
  const float* w3 = (const float*)d_in[7];
  const float* b3 = (const float*)d_in[8];
  float* out = (float*)d_out;

  char* ws = (char*)d_ws;
  float2* psi = (float2*)ws;                       // 24*16384*8 = 3,145,728 B
  float2* Xf  = (float2*)(ws + 3145728);           // 64*16384*8 = 8,388,608 B
  float*  s0  = (float*)(ws + 3145728 + 8388608);  // 64
  float*  s1n = s0 + 64;                           // 384
  float*  s2n = s1n + 384;                         // 960

  hipMemsetAsync(s1n, 0, (384 + 960) * sizeof(float), stream);
  k_psi<<<dim3(1536), dim3(256), 0, stream>>>(mags, phases, psi);
  k_img_fft<<<dim3(64), dim3(NT), 0, stream>>>(image, Xf, s0);
  k_scat<<<dim3(1536), dim3(NT), 0, stream>>>(Xf, psi, s1n, s2n);
  k_final<<<dim3(1), dim3(64), 0, stream>>>(s0, s1n, s2n, w1, b1, w2, b2, w3, b3, out);
}